// Round 13
// baseline (386.614 us; speedup 1.0000x reference)
//
#include <hip/hip_runtime.h>
#include <hip/hip_bf16.h>

// Problem: B=32, T=256, I=128, H=128, C=100. All fp32.
// out = (h_T + attn_c_final) @ w_fc.T + b_fc; only the LAST step's attention
// matters (scan carry overwrites attn_c each step).
//
// Structure (r11 -> r12): 2 dispatches.
//  1. prep: weight conversion/packing (W2ih, W2v split-bf16, whh_pk, bias)
//  2. lstm_fused mega-kernel, one block per batch:
//     phase 0: G[b] = x[b] @ W_ih^T + bias via MFMA (6144 MFMA/block,
//              ~12.5us) -- replaces the separate 1024-block gemmG dispatch
//              whose true cost was dominated by dispatch overhead (r11
//              accounting: prep+gemmG+gaps = 89us vs ~12us of work).
//              G write->read is now L2-local (512KB/block, 4 blocks/XCD).
//     phase 1: r2's 201us recurrence (asm pk_fma, raw lgkm-only barrier)
//     phase 2: r11's fused attention tail (q, KV MFMA, scores, attn, FC)
// Recurrence wall (r0-r8): VALU issue + AGPR-copy tax (no VALU op sources
// AGPRs, r4 assembler proof) + latency ~= 1900 cyc/step; MFMA recurrence
// measured worse (3080 cyc/step, r8). 201us is the floor for that phase.

#define Bsz 32
#define Tsz 256
#define Isz 128
#define Hsz 128
#define Csz 100
#define G4H 512   // 4*H

typedef short v8s __attribute__((ext_vector_type(8)));   // 8 bf16 = 4 VGPRs
typedef float v4fa __attribute__((ext_vector_type(4)));  // MFMA acc

// ---------------- device helpers ----------------
__device__ __forceinline__ float2 pk_fma(float2 a, float2 b, float2 c) {
    float2 d;
    asm("v_pk_fma_f32 %0, %1, %2, %3" : "=v"(d) : "v"(a), "v"(b), "v"(c));
    return d;
}
__device__ __forceinline__ float quad_rsum(float x) {
    int t = __builtin_amdgcn_update_dpp(0, __float_as_int(x), 0xB1, 0xF, 0xF, true); // xor 1
    x += __int_as_float(t);
    t = __builtin_amdgcn_update_dpp(0, __float_as_int(x), 0x4E, 0xF, 0xF, true);     // xor 2
    x += __int_as_float(t);
    return x;
}
// 8-lane sum within aligned 8-lane groups: xor1, xor2, half-row mirror
__device__ __forceinline__ float oct_rsum(float x) {
    int t = __builtin_amdgcn_update_dpp(0, __float_as_int(x), 0xB1, 0xF, 0xF, true);
    x += __int_as_float(t);
    t = __builtin_amdgcn_update_dpp(0, __float_as_int(x), 0x4E, 0xF, 0xF, true);
    x += __int_as_float(t);
    t = __builtin_amdgcn_update_dpp(0, __float_as_int(x), 0x141, 0xF, 0xF, true);
    x += __int_as_float(t);
    return x;
}
__device__ __forceinline__ float rcpf(float x) { return __builtin_amdgcn_rcpf(x); }
__device__ __forceinline__ float ex2(float x) { return __builtin_amdgcn_exp2f(x); }
__device__ __forceinline__ float sigm_n(float x) {
    return rcpf(1.0f + ex2(-1.442695041f * x));
}
__device__ __forceinline__ float tanh_n(float x) {
    return fmaf(-2.0f, rcpf(1.0f + ex2(2.885390082f * x)), 1.0f);
}
__device__ __forceinline__ short bf16_bits(float x) {
    __hip_bfloat16 h = __float2bfloat16(x);
    return *reinterpret_cast<short*>(&h);
}
__device__ __forceinline__ float bf16_val(float x) {
    return __bfloat162float(__float2bfloat16(x));
}

// ---------------- kernel 0: weight prep ----------------
// whh_pk: packed for lstm (r2 layout). bias = b_ih + b_hh.
// W2ih[n][k'] (512 x 384 bf16): [w_hi | w_lo | w_hi]  (pairs with A=[hi|hi|lo])
// W2v [n][k'] (128 x 384 bf16): transpose-split of w1 bottom half.
__global__ __launch_bounds__(256) void prep_kernel(
    const float* __restrict__ w_ih, const float* __restrict__ b_ih,
    const float* __restrict__ w_hh, const float* __restrict__ b_hh,
    const float* __restrict__ w1,
    __hip_bfloat16* __restrict__ W2ih, __hip_bfloat16* __restrict__ W2v,
    float* __restrict__ whh_pk, float* __restrict__ bias) {
    int idx = blockIdx.x * blockDim.x + threadIdx.x;   // 0..65535
    if (idx < G4H * Isz) {
        int n = idx >> 7;
        int k = idx & 127;
        float x = w_ih[idx];
        __hip_bfloat16 hi = __float2bfloat16(x);
        __hip_bfloat16 lo = __float2bfloat16(x - __bfloat162float(hi));
        W2ih[(size_t)n * 384 + k] = hi;
        W2ih[(size_t)n * 384 + 128 + k] = lo;
        W2ih[(size_t)n * 384 + 256 + k] = hi;

        int j4  = idx & 3;
        int q   = (idx >> 2) & 3;
        int d   = (idx >> 4) & 127;
        int gi  = (idx >> 11) & 3;
        int kk4 = (idx >> 13) & 7;
        whh_pk[idx] = w_hh[(size_t)((gi << 7) + d) * 128 + (q << 5) + (kk4 << 2) + j4];
    }
    if (idx < Hsz * Hsz) {
        int n = idx >> 7;          // output col of KV
        int k = idx & 127;
        float x = w1[(size_t)(128 + k) * Hsz + n];
        __hip_bfloat16 hi = __float2bfloat16(x);
        __hip_bfloat16 lo = __float2bfloat16(x - __bfloat162float(hi));
        W2v[(size_t)n * 384 + k] = hi;
        W2v[(size_t)n * 384 + 128 + k] = lo;
        W2v[(size_t)n * 384 + 256 + k] = hi;
    }
    if (idx < G4H) bias[idx] = b_ih[idx] + b_hh[idx];
}

// ---------------- mega kernel: G-gemm + sequential LSTM + attention tail ----
#define HPAD(k) ((k) + 8 * ((k) >> 5))

__global__ __launch_bounds__(512, 2) void lstm_fused(
    const float* __restrict__ x, const __hip_bfloat16* __restrict__ W2ih,
    const float* __restrict__ bias,
    const float* __restrict__ whh_pk,
    const __hip_bfloat16* __restrict__ W2v,
    const float* __restrict__ w1, const float* __restrict__ w2,
    const float* __restrict__ w_fc, const float* __restrict__ b_fc,
    float* __restrict__ G, float* __restrict__ H_all,
    float* __restrict__ out) {
    const int b = blockIdx.x;
    const int tid = threadIdx.x;
    const int d = tid >> 2;
    const int q = tid & 3;
    const int w_id = tid >> 6;
    const int lane = tid & 63;
    const int fr = lane & 15, fq = lane >> 4;

    __shared__ float h_s[2][160];
    __shared__ float kv_s[64][132];
    __shared__ float hT_s[Hsz];
    __shared__ float q_s[Hsz];
    __shared__ float w2s[Hsz];
    __shared__ float r_s[Hsz];
    __shared__ float s_s[64];
    __shared__ float part4[4][Hsz];

    float* Gb = G + (size_t)b * Tsz * G4H;

    // ================= phase 0: G[b] = x[b] @ W_ih^T + bias =================
    // 8 waves; wave w owns rows [w*32, w*32+32), loops 16 N-tiles of 32.
    {
        const float* Ab = x + (size_t)b * Tsz * Isz;
        const int m0 = w_id * 32;

        v8s Ahi[2][4], Alo[2][4];
        #pragma unroll
        for (int i = 0; i < 2; ++i)
            #pragma unroll
            for (int cb = 0; cb < 4; ++cb) {
                const float* src = Ab + (size_t)(m0 + 16 * i + fr) * Isz + cb * 32 + fq * 8;
                float4 f0 = *(const float4*)src;
                float4 f1 = *(const float4*)(src + 4);
                float f[8] = {f0.x, f0.y, f0.z, f0.w, f1.x, f1.y, f1.z, f1.w};
                v8s hi, lo;
                #pragma unroll
                for (int e = 0; e < 8; ++e) {
                    float hv = bf16_val(f[e]);
                    hi[e] = bf16_bits(f[e]);
                    lo[e] = bf16_bits(f[e] - hv);
                }
                Ahi[i][cb] = hi;
                Alo[i][cb] = lo;
            }

        const short* Wb = (const short*)W2ih;
        for (int nt = 0; nt < 16; ++nt) {
            const int n0 = nt * 32;
            v4fa acc[2][2] = {};
            #pragma unroll
            for (int ks = 0; ks < 12; ++ks) {
                int cb = ks & 3;
                v8s a0 = (ks >= 8) ? Alo[0][cb] : Ahi[0][cb];
                v8s a1 = (ks >= 8) ? Alo[1][cb] : Ahi[1][cb];
                int kb = ks * 32 + fq * 8;
                v8s b0 = *(const v8s*)(Wb + (size_t)(n0 + fr) * 384 + kb);
                v8s b1 = *(const v8s*)(Wb + (size_t)(n0 + 16 + fr) * 384 + kb);
                acc[0][0] = __builtin_amdgcn_mfma_f32_16x16x32_bf16(a0, b0, acc[0][0], 0, 0, 0);
                acc[0][1] = __builtin_amdgcn_mfma_f32_16x16x32_bf16(a0, b1, acc[0][1], 0, 0, 0);
                acc[1][0] = __builtin_amdgcn_mfma_f32_16x16x32_bf16(a1, b0, acc[1][0], 0, 0, 0);
                acc[1][1] = __builtin_amdgcn_mfma_f32_16x16x32_bf16(a1, b1, acc[1][1], 0, 0, 0);
            }
            // C/D layout: col = lane&15, row = quad*4 + reg
            #pragma unroll
            for (int i = 0; i < 2; ++i)
                #pragma unroll
                for (int j = 0; j < 2; ++j) {
                    int cn = n0 + 16 * j + fr;
                    float bb = bias[cn];
                    #pragma unroll
                    for (int rr = 0; rr < 4; ++rr) {
                        int row = m0 + 16 * i + fq * 4 + rr;
                        Gb[(size_t)row * G4H + cn] = acc[i][j][rr] + bb;
                    }
                }
        }
    }
    __syncthreads();   // full drain: G stores visible block-locally (same L2)

    // ================= phase 1: recurrence (r2 structure, 201us) ============
    float2 w2v[4][16];
    {
        const float4* wp = (const float4*)whh_pk;
        #pragma unroll
        for (int kk4 = 0; kk4 < 8; ++kk4)
            #pragma unroll
            for (int gi = 0; gi < 4; ++gi) {
                float4 v = wp[((kk4 * 4 + gi) * 128 + d) * 4 + q];
                w2v[gi][kk4 * 2]     = make_float2(v.x, v.y);
                w2v[gi][kk4 * 2 + 1] = make_float2(v.z, v.w);
            }
    }

    if (tid < 320) ((float*)h_s)[tid] = 0.0f;
    float c = 0.0f;
    __syncthreads();

    const float* Gq = Gb + q * 128 + d;
    float* Hst = H_all + (size_t)b * Tsz * Hsz + d;

    float gval = Gq[0];
    int cur = 0;
    for (int t = 0; t < Tsz; ++t) {
        const int tn = (t < Tsz - 1) ? t + 1 : t;
        float ngval = Gq[(size_t)tn * G4H];   // prefetch; stays in flight
                                              // across the raw barrier

        float2 accA[4], accB[4];
        #pragma unroll
        for (int gi = 0; gi < 4; ++gi) {
            accA[gi] = make_float2(q == gi ? gval : 0.f, 0.f);
            accB[gi] = make_float2(0.f, 0.f);
        }
        const float4* hb4 = (const float4*)&h_s[cur][q * 40];  // HPAD(q*32)=q*40
        #pragma unroll
        for (int kk4 = 0; kk4 < 8; ++kk4) {
            float4 h4 = hb4[kk4];
            float2 hA = make_float2(h4.x, h4.y);
            float2 hB = make_float2(h4.z, h4.w);
            accA[0] = pk_fma(hA, w2v[0][2 * kk4], accA[0]);
            accA[1] = pk_fma(hA, w2v[1][2 * kk4], accA[1]);
            accA[2] = pk_fma(hA, w2v[2][2 * kk4], accA[2]);
            accA[3] = pk_fma(hA, w2v[3][2 * kk4], accA[3]);
            accB[0] = pk_fma(hB, w2v[0][2 * kk4 + 1], accB[0]);
            accB[1] = pk_fma(hB, w2v[1][2 * kk4 + 1], accB[1]);
            accB[2] = pk_fma(hB, w2v[2][2 * kk4 + 1], accB[2]);
            accB[3] = pk_fma(hB, w2v[3][2 * kk4 + 1], accB[3]);
        }
        float a0 = quad_rsum(accA[0].x + accA[0].y + accB[0].x + accB[0].y);
        float a1 = quad_rsum(accA[1].x + accA[1].y + accB[1].x + accB[1].y);
        float a2 = quad_rsum(accA[2].x + accA[2].y + accB[2].x + accB[2].y);
        float a3 = quad_rsum(accA[3].x + accA[3].y + accB[3].x + accB[3].y);

        float iv = sigm_n(a0);
        float fv = sigm_n(a1);
        float gv = tanh_n(a2);
        float ov = sigm_n(a3);
        c = fmaf(fv, c, iv * gv);
        float h = ov * tanh_n(c);

        if (q == 0) {
            h_s[cur ^ 1][HPAD(d)] = h;
            Hst[(size_t)t * Hsz] = h;
        }
        gval = ngval;
        // ---- raw barrier: wait LDS only, leave global load/store in flight
        __builtin_amdgcn_sched_barrier(0);
        asm volatile("s_waitcnt lgkmcnt(0)" ::: "memory");
        __builtin_amdgcn_s_barrier();
        __builtin_amdgcn_sched_barrier(0);
        cur ^= 1;
    }

    // ================= phase 2: fused attention tail =================
    __syncthreads();   // full drain: H_all stores visible

    const float* Hb = H_all + (size_t)b * Tsz * Hsz;
    const int n_a = tid >> 2;

    // Phase A: q_s = hT @ w1_top; stage hT and w2 in LDS
    {
        if (tid < Hsz) {
            hT_s[tid] = h_s[cur][HPAD(tid)];
            w2s[tid] = w2[tid];
        }
        float acc = 0.f;
        #pragma unroll 8
        for (int kk = 0; kk < 32; ++kk) {
            int k = q * 32 + kk;
            acc = fmaf(h_s[cur][HPAD(k)], w1[(size_t)k * Hsz + n_a], acc);
        }
        acc = quad_rsum(acc);
        if (q == 0) q_s[n_a] = acc;
    }
    __syncthreads();

    // Phase B: 4 jt-tiles of 64 slots: KV (MFMA) -> scores -> attn partial
    const int d_att = tid & 127, grp = tid >> 7;
    float racc = 0.f;

    for (int jt = 0; jt < 4; ++jt) {
        // B1: KV tile rows jt*64..+64, cols 0..128, 8 waves (one 32x32 each)
        {
            const int m0 = (w_id & 1) * 32;
            const int n0 = (w_id >> 1) * 32;
            const float* Abase = Hb + (size_t)(jt * 64) * Hsz;

            v8s Ahi[2][4], Alo[2][4];
            #pragma unroll
            for (int i = 0; i < 2; ++i)
                #pragma unroll
                for (int cb = 0; cb < 4; ++cb) {
                    const float* src = Abase + (size_t)(m0 + 16 * i + fr) * Hsz + cb * 32 + fq * 8;
                    float4 f0 = *(const float4*)src;
                    float4 f1 = *(const float4*)(src + 4);
                    float f[8] = {f0.x, f0.y, f0.z, f0.w, f1.x, f1.y, f1.z, f1.w};
                    v8s hi, lo;
                    #pragma unroll
                    for (int e = 0; e < 8; ++e) {
                        float hv = bf16_val(f[e]);
                        hi[e] = bf16_bits(f[e]);
                        lo[e] = bf16_bits(f[e] - hv);
                    }
                    Ahi[i][cb] = hi;
                    Alo[i][cb] = lo;
                }

            v4fa a2[2][2] = {};
            const short* Wb = (const short*)W2v;
            #pragma unroll
            for (int ks = 0; ks < 12; ++ks) {
                int cb = ks & 3;
                v8s a0 = (ks >= 8) ? Alo[0][cb] : Ahi[0][cb];
                v8s a1 = (ks >= 8) ? Alo[1][cb] : Ahi[1][cb];
                int kb = ks * 32 + fq * 8;
                v8s b0 = *(const v8s*)(Wb + (size_t)(n0 + fr) * 384 + kb);
                v8s b1 = *(const v8s*)(Wb + (size_t)(n0 + 16 + fr) * 384 + kb);
                a2[0][0] = __builtin_amdgcn_mfma_f32_16x16x32_bf16(a0, b0, a2[0][0], 0, 0, 0);
                a2[0][1] = __builtin_amdgcn_mfma_f32_16x16x32_bf16(a0, b1, a2[0][1], 0, 0, 0);
                a2[1][0] = __builtin_amdgcn_mfma_f32_16x16x32_bf16(a1, b0, a2[1][0], 0, 0, 0);
                a2[1][1] = __builtin_amdgcn_mfma_f32_16x16x32_bf16(a1, b1, a2[1][1], 0, 0, 0);
            }
            #pragma unroll
            for (int i = 0; i < 2; ++i)
                #pragma unroll
                for (int j = 0; j < 2; ++j)
                    #pragma unroll
                    for (int rr = 0; rr < 4; ++rr)
                        kv_s[m0 + 16 * i + fq * 4 + rr][n0 + 16 * j + fr] = a2[i][j][rr];
        }
        __syncthreads();

        // B2: scores, one 8-lane group per slot (64 slots)
        {
            const int jl = tid >> 3, oct = tid & 7;
            float p = 0.f;
            #pragma unroll
            for (int kk = 0; kk < 16; ++kk) {
                int k = oct * 16 + kk;
                p = fmaf(tanh_n(q_s[k] + kv_s[jl][k]), w2s[k], p);
            }
            p = oct_rsum(p);
            if (oct == 0) s_s[jl] = (jt * 64 + jl < 255) ? p : 0.0f;
        }
        __syncthreads();

        // B3: attn partial: racc += s[j] * H[j][d] over this tile's 16 j/grp
        #pragma unroll 4
        for (int u = 0; u < 16; ++u) {
            int lj = grp * 16 + u;
            racc = fmaf(s_s[lj], Hb[(size_t)(jt * 64 + lj) * Hsz + d_att], racc);
        }
        __syncthreads();   // protect kv_s / s_s before next jt overwrites
    }

    part4[grp][d_att] = racc;
    __syncthreads();
    if (tid < Hsz)
        r_s[tid] = hT_s[tid] + part4[0][tid] + part4[1][tid] + part4[2][tid] + part4[3][tid];
    __syncthreads();

    // Phase C: out[b] = r @ w_fc^T + b_fc (one quad per output)
    {
        const int o = tid >> 2;
        float acc = 0.f;
        if (o < Csz) {
            #pragma unroll 8
            for (int kk = 0; kk < 32; ++kk) {
                int k = q * 32 + kk;
                acc = fmaf(r_s[k], w_fc[(size_t)o * Hsz + k], acc);
            }
        }
        acc = quad_rsum(acc);
        if (q == 0 && o < Csz) out[b * Csz + o] = acc + b_fc[o];
    }
}

// ---------------- launch ----------------
extern "C" void kernel_launch(void* const* d_in, const int* in_sizes, int n_in,
                              void* d_out, int out_size, void* d_ws, size_t ws_size,
                              hipStream_t stream) {
    const float* x    = (const float*)d_in[0];
    const float* w_ih = (const float*)d_in[1];
    const float* b_ih = (const float*)d_in[2];
    const float* w_hh = (const float*)d_in[3];
    const float* b_hh = (const float*)d_in[4];
    const float* w1   = (const float*)d_in[5];
    const float* w2   = (const float*)d_in[6];
    const float* w_fc = (const float*)d_in[7];
    const float* b_fc = (const float*)d_in[8];

    float* ws = (float*)d_ws;
    float* whh_pk = ws;                               // 65536 f
    float* bias   = whh_pk + 65536;                   // 512 f
    __hip_bfloat16* W2ih = (__hip_bfloat16*)(bias + 512);            // 98304 f
    __hip_bfloat16* W2v  = (__hip_bfloat16*)(bias + 512 + 98304);    // 24576 f
    float* G      = bias + 512 + 98304 + 24576;       // 8192*512 = 4194304 f
    float* H_all  = G + 4194304;                      // 1048576 f
    // total ~5.43M floats ~= 21.7 MB

    prep_kernel<<<256, 256, 0, stream>>>(w_ih, b_ih, w_hh, b_hh, w1,
                                         W2ih, W2v, whh_pk, bias);

    lstm_fused<<<Bsz, 512, 0, stream>>>(x, W2ih, bias, whh_pk, W2v,
                                        w1, w2, w_fc, b_fc,
                                        G, H_all, (float*)d_out);
}

// Round 14
// 309.917 us; speedup vs baseline: 1.2475x; 1.2475x over previous
//
#include <hip/hip_runtime.h>
#include <hip/hip_bf16.h>

// Problem: B=32, T=256, I=128, H=128, C=100. All fp32.
// out = (h_T + attn_c_final) @ w_fc.T + b_fc; only the LAST step's attention
// matters (scan carry overwrites attn_c each step).
//
// Structure (r14): 2 dispatches, both at full parallelism where it matters.
//  1. gemm_prep (grid 1408 x 256):
//     blocks 0..1023:   G = x @ W_ih^T + (b_ih+b_hh), MFMA split-bf16,
//                       with w_ih converted to hi/lo fragments IN-REGISTER
//                       (no dependency on a prep pass; w_ih is L2-hot).
//     blocks 1024..1407: pack whh_pk (lstm weight layout) + W2v (split-bf16
//                       transpose of w1 bottom half) for dispatch 2.
//  2. lstm_fused (32 x 512): r11's measured-222.6us kernel, byte-identical:
//     r2's 201us recurrence (asm pk_fma + raw lgkm-only barrier) + in-block
//     attention tail (q, KV MFMA, scores, attn partial, FC), ~21.5us.
//
// Lessons driving this shape:
//  - r13: moving the G-GEMM into the 32-block kernel cost 92us (vs 12.5
//    predicted) -- 2 waves/SIMD cannot hide GEMM memory latency; large
//    parallel work must stay in its own wide dispatch.
//  - overhead model (r9/r11/r13 fits): non-kernel ~= 40us fixed + ~16us per
//    dispatch -> only cheap lever left is dispatch count.
//  - recurrence wall (r0-r8): ~1900 cyc/step (VALU issue + unremovable
//    AGPR-copy tax: no VALU op sources AGPRs, r4 assembler proof). 201us.

#define Bsz 32
#define Tsz 256
#define Isz 128
#define Hsz 128
#define Csz 100
#define G4H 512   // 4*H

typedef short v8s __attribute__((ext_vector_type(8)));   // 8 bf16 = 4 VGPRs
typedef float v4fa __attribute__((ext_vector_type(4)));  // MFMA acc

// ---------------- device helpers ----------------
__device__ __forceinline__ float2 pk_fma(float2 a, float2 b, float2 c) {
    float2 d;
    asm("v_pk_fma_f32 %0, %1, %2, %3" : "=v"(d) : "v"(a), "v"(b), "v"(c));
    return d;
}
__device__ __forceinline__ float quad_rsum(float x) {
    int t = __builtin_amdgcn_update_dpp(0, __float_as_int(x), 0xB1, 0xF, 0xF, true); // xor 1
    x += __int_as_float(t);
    t = __builtin_amdgcn_update_dpp(0, __float_as_int(x), 0x4E, 0xF, 0xF, true);     // xor 2
    x += __int_as_float(t);
    return x;
}
// 8-lane sum within aligned 8-lane groups: xor1, xor2, half-row mirror
__device__ __forceinline__ float oct_rsum(float x) {
    int t = __builtin_amdgcn_update_dpp(0, __float_as_int(x), 0xB1, 0xF, 0xF, true);
    x += __int_as_float(t);
    t = __builtin_amdgcn_update_dpp(0, __float_as_int(x), 0x4E, 0xF, 0xF, true);
    x += __int_as_float(t);
    t = __builtin_amdgcn_update_dpp(0, __float_as_int(x), 0x141, 0xF, 0xF, true);
    x += __int_as_float(t);
    return x;
}
__device__ __forceinline__ float rcpf(float x) { return __builtin_amdgcn_rcpf(x); }
__device__ __forceinline__ float ex2(float x) { return __builtin_amdgcn_exp2f(x); }
__device__ __forceinline__ float sigm_n(float x) {
    return rcpf(1.0f + ex2(-1.442695041f * x));
}
__device__ __forceinline__ float tanh_n(float x) {
    return fmaf(-2.0f, rcpf(1.0f + ex2(2.885390082f * x)), 1.0f);
}
__device__ __forceinline__ short bf16_bits(float x) {
    __hip_bfloat16 h = __float2bfloat16(x);
    return *reinterpret_cast<short*>(&h);
}
__device__ __forceinline__ float bf16_val(float x) {
    return __bfloat162float(__float2bfloat16(x));
}

// ---------------- kernel 1: fused gemmG + prep ----------------
// blocks < 1024: one 64x64 tile of G = x @ w_ih^T + (b_ih + b_hh).
//   A (x rows) AND B (w_ih rows) both converted fp32 -> hi/lo bf16 frags
//   in-register. 12 k-steps: ks0-3 A_hi*B_hi, 4-7 A_hi*B_lo, 8-11 A_lo*B_hi.
// blocks >= 1024: element-wise packing of whh_pk and W2v.
__global__ __launch_bounds__(256) void gemm_prep(
    const float* __restrict__ x, const float* __restrict__ w_ih,
    const float* __restrict__ b_ih, const float* __restrict__ w_hh,
    const float* __restrict__ b_hh, const float* __restrict__ w1,
    __hip_bfloat16* __restrict__ W2v, float* __restrict__ whh_pk,
    float* __restrict__ G) {
    const int bid = blockIdx.x;
    const int tid = threadIdx.x;

    if (bid >= 1024) {
        int idx = (bid - 1024) * 256 + tid;        // 0..98303
        if (idx < 65536) {
            // whh_pk: r2 lstm layout (float4-coalesced per-thread slices)
            int j4  = idx & 3;
            int q   = (idx >> 2) & 3;
            int d   = (idx >> 4) & 127;
            int gi  = (idx >> 11) & 3;
            int kk4 = (idx >> 13) & 7;
            whh_pk[idx] = w_hh[(size_t)((gi << 7) + d) * 128 + (q << 5) + (kk4 << 2) + j4];
        } else if (idx < 65536 + 16384) {
            int t = idx - 65536;
            int n = t >> 7;            // output col of KV
            int k = t & 127;
            float v = w1[(size_t)(128 + k) * Hsz + n];
            __hip_bfloat16 hi = __float2bfloat16(v);
            __hip_bfloat16 lo = __float2bfloat16(v - __bfloat162float(hi));
            W2v[(size_t)n * 384 + k] = hi;
            W2v[(size_t)n * 384 + 128 + k] = lo;
            W2v[(size_t)n * 384 + 256 + k] = hi;
        }
        return;
    }

    // ---- gemmG tile: m-tile = bid>>3, n-tile = bid&7
    const int w = tid >> 6, lane = tid & 63;
    const int m0 = (bid >> 3) * 64 + (w & 1) * 32;
    const int n0 = (bid & 7) * 64 + (w >> 1) * 32;
    const int r = lane & 15, quad = lane >> 4;

    v8s Ahi[2][4], Alo[2][4];
    #pragma unroll
    for (int i = 0; i < 2; ++i)
        #pragma unroll
        for (int cb = 0; cb < 4; ++cb) {
            const float* src = x + (size_t)(m0 + 16 * i + r) * Isz + cb * 32 + quad * 8;
            float4 f0 = *(const float4*)src;
            float4 f1 = *(const float4*)(src + 4);
            float f[8] = {f0.x, f0.y, f0.z, f0.w, f1.x, f1.y, f1.z, f1.w};
            v8s hi, lo;
            #pragma unroll
            for (int e = 0; e < 8; ++e) {
                float hv = bf16_val(f[e]);
                hi[e] = bf16_bits(f[e]);
                lo[e] = bf16_bits(f[e] - hv);
            }
            Ahi[i][cb] = hi;
            Alo[i][cb] = lo;
        }

    v8s Bhi[2][4], Blo[2][4];    // j: n-subtile (n0+16j+r row of w_ih)
    #pragma unroll
    for (int j = 0; j < 2; ++j)
        #pragma unroll
        for (int cb = 0; cb < 4; ++cb) {
            const float* src = w_ih + (size_t)(n0 + 16 * j + r) * Isz + cb * 32 + quad * 8;
            float4 f0 = *(const float4*)src;
            float4 f1 = *(const float4*)(src + 4);
            float f[8] = {f0.x, f0.y, f0.z, f0.w, f1.x, f1.y, f1.z, f1.w};
            v8s hi, lo;
            #pragma unroll
            for (int e = 0; e < 8; ++e) {
                float hv = bf16_val(f[e]);
                hi[e] = bf16_bits(f[e]);
                lo[e] = bf16_bits(f[e] - hv);
            }
            Bhi[j][cb] = hi;
            Blo[j][cb] = lo;
        }

    v4fa acc[2][2] = {};
    #pragma unroll
    for (int ks = 0; ks < 12; ++ks) {
        int cb = ks & 3;
        bool blo = (ks >= 4) && (ks < 8);
        v8s a0 = (ks >= 8) ? Alo[0][cb] : Ahi[0][cb];
        v8s a1 = (ks >= 8) ? Alo[1][cb] : Ahi[1][cb];
        v8s b0 = blo ? Blo[0][cb] : Bhi[0][cb];
        v8s b1 = blo ? Blo[1][cb] : Bhi[1][cb];
        acc[0][0] = __builtin_amdgcn_mfma_f32_16x16x32_bf16(a0, b0, acc[0][0], 0, 0, 0);
        acc[0][1] = __builtin_amdgcn_mfma_f32_16x16x32_bf16(a0, b1, acc[0][1], 0, 0, 0);
        acc[1][0] = __builtin_amdgcn_mfma_f32_16x16x32_bf16(a1, b0, acc[1][0], 0, 0, 0);
        acc[1][1] = __builtin_amdgcn_mfma_f32_16x16x32_bf16(a1, b1, acc[1][1], 0, 0, 0);
    }
    // C/D layout: col = lane&15, row = quad*4 + reg  [verified m89/m91]
    #pragma unroll
    for (int i = 0; i < 2; ++i)
        #pragma unroll
        for (int j = 0; j < 2; ++j) {
            int cn = n0 + 16 * j + r;
            float bb = b_ih[cn] + b_hh[cn];
            #pragma unroll
            for (int rr = 0; rr < 4; ++rr) {
                int row = m0 + 16 * i + quad * 4 + rr;
                G[(size_t)row * G4H + cn] = acc[i][j][rr] + bb;
            }
        }
}

// ---------------- kernel 2: sequential LSTM + fused attention tail ----------------
// Byte-identical to r11's measured 222.6us kernel.
#define HPAD(k) ((k) + 8 * ((k) >> 5))

__global__ __launch_bounds__(512, 2) void lstm_fused(
    const float* __restrict__ G, const float* __restrict__ whh_pk,
    const __hip_bfloat16* __restrict__ W2v,
    const float* __restrict__ w1, const float* __restrict__ w2,
    const float* __restrict__ w_fc, const float* __restrict__ b_fc,
    float* __restrict__ H_all, float* __restrict__ out) {
    const int b = blockIdx.x;
    const int tid = threadIdx.x;
    const int d = tid >> 2;
    const int q = tid & 3;

    __shared__ float h_s[2][160];
    __shared__ float kv_s[64][132];
    __shared__ float hT_s[Hsz];
    __shared__ float q_s[Hsz];
    __shared__ float w2s[Hsz];
    __shared__ float r_s[Hsz];
    __shared__ float s_s[64];
    __shared__ float part4[4][Hsz];

    // ================= recurrence (r2 structure, 201us) =================
    float2 w2v[4][16];
    {
        const float4* wp = (const float4*)whh_pk;
        #pragma unroll
        for (int kk4 = 0; kk4 < 8; ++kk4)
            #pragma unroll
            for (int gi = 0; gi < 4; ++gi) {
                float4 v = wp[((kk4 * 4 + gi) * 128 + d) * 4 + q];
                w2v[gi][kk4 * 2]     = make_float2(v.x, v.y);
                w2v[gi][kk4 * 2 + 1] = make_float2(v.z, v.w);
            }
    }

    if (tid < 320) ((float*)h_s)[tid] = 0.0f;
    float c = 0.0f;
    __syncthreads();   // once, before the loop: full drain is fine here

    const float* Gq = G + (size_t)b * Tsz * G4H + q * 128 + d;
    float* Hst = H_all + (size_t)b * Tsz * Hsz + d;

    float gval = Gq[0];
    int cur = 0;
    for (int t = 0; t < Tsz; ++t) {
        const int tn = (t < Tsz - 1) ? t + 1 : t;
        float ngval = Gq[(size_t)tn * G4H];   // prefetch; stays in flight
                                              // across the raw barrier

        float2 accA[4], accB[4];
        #pragma unroll
        for (int gi = 0; gi < 4; ++gi) {
            accA[gi] = make_float2(q == gi ? gval : 0.f, 0.f);
            accB[gi] = make_float2(0.f, 0.f);
        }
        const float4* hb4 = (const float4*)&h_s[cur][q * 40];  // HPAD(q*32)=q*40
        #pragma unroll
        for (int kk4 = 0; kk4 < 8; ++kk4) {
            float4 h4 = hb4[kk4];
            float2 hA = make_float2(h4.x, h4.y);
            float2 hB = make_float2(h4.z, h4.w);
            accA[0] = pk_fma(hA, w2v[0][2 * kk4], accA[0]);
            accA[1] = pk_fma(hA, w2v[1][2 * kk4], accA[1]);
            accA[2] = pk_fma(hA, w2v[2][2 * kk4], accA[2]);
            accA[3] = pk_fma(hA, w2v[3][2 * kk4], accA[3]);
            accB[0] = pk_fma(hB, w2v[0][2 * kk4 + 1], accB[0]);
            accB[1] = pk_fma(hB, w2v[1][2 * kk4 + 1], accB[1]);
            accB[2] = pk_fma(hB, w2v[2][2 * kk4 + 1], accB[2]);
            accB[3] = pk_fma(hB, w2v[3][2 * kk4 + 1], accB[3]);
        }
        float a0 = quad_rsum(accA[0].x + accA[0].y + accB[0].x + accB[0].y);
        float a1 = quad_rsum(accA[1].x + accA[1].y + accB[1].x + accB[1].y);
        float a2 = quad_rsum(accA[2].x + accA[2].y + accB[2].x + accB[2].y);
        float a3 = quad_rsum(accA[3].x + accA[3].y + accB[3].x + accB[3].y);

        float iv = sigm_n(a0);
        float fv = sigm_n(a1);
        float gv = tanh_n(a2);
        float ov = sigm_n(a3);
        c = fmaf(fv, c, iv * gv);
        float h = ov * tanh_n(c);

        if (q == 0) {
            h_s[cur ^ 1][HPAD(d)] = h;
            Hst[(size_t)t * Hsz] = h;
        }
        gval = ngval;
        // ---- raw barrier: wait LDS only, leave global load/store in flight
        __builtin_amdgcn_sched_barrier(0);
        asm volatile("s_waitcnt lgkmcnt(0)" ::: "memory");
        __builtin_amdgcn_s_barrier();
        __builtin_amdgcn_sched_barrier(0);
        cur ^= 1;
    }

    // ================= fused attention tail =================
    __syncthreads();   // full drain: H_all stores visible block-locally

    const float* Hb = H_all + (size_t)b * Tsz * Hsz;
    const int n_a = tid >> 2;

    // Phase A: q_s = hT @ w1_top; stage hT and w2 in LDS
    {
        if (tid < Hsz) {
            hT_s[tid] = h_s[cur][HPAD(tid)];
            w2s[tid] = w2[tid];
        }
        float acc = 0.f;
        #pragma unroll 8
        for (int kk = 0; kk < 32; ++kk) {
            int k = q * 32 + kk;
            acc = fmaf(h_s[cur][HPAD(k)], w1[(size_t)k * Hsz + n_a], acc);
        }
        acc = quad_rsum(acc);
        if (q == 0) q_s[n_a] = acc;
    }
    __syncthreads();

    // Phase B: 4 jt-tiles of 64 slots: KV (MFMA) -> scores -> attn partial
    const int w_id = tid >> 6;
    const int lane = tid & 63;
    const int fr = lane & 15, fq = lane >> 4;
    const int d_att = tid & 127, grp = tid >> 7;
    float racc = 0.f;

    for (int jt = 0; jt < 4; ++jt) {
        // B1: KV tile rows jt*64..+64, cols 0..128, 8 waves (one 32x32 each)
        {
            const int m0 = (w_id & 1) * 32;
            const int n0 = (w_id >> 1) * 32;
            const float* Abase = Hb + (size_t)(jt * 64) * Hsz;

            v8s Ahi[2][4], Alo[2][4];
            #pragma unroll
            for (int i = 0; i < 2; ++i)
                #pragma unroll
                for (int cb = 0; cb < 4; ++cb) {
                    const float* src = Abase + (size_t)(m0 + 16 * i + fr) * Hsz + cb * 32 + fq * 8;
                    float4 f0 = *(const float4*)src;
                    float4 f1 = *(const float4*)(src + 4);
                    float f[8] = {f0.x, f0.y, f0.z, f0.w, f1.x, f1.y, f1.z, f1.w};
                    v8s hi, lo;
                    #pragma unroll
                    for (int e = 0; e < 8; ++e) {
                        float hv = bf16_val(f[e]);
                        hi[e] = bf16_bits(f[e]);
                        lo[e] = bf16_bits(f[e] - hv);
                    }
                    Ahi[i][cb] = hi;
                    Alo[i][cb] = lo;
                }

            v4fa a2[2][2] = {};
            const short* Wb = (const short*)W2v;
            #pragma unroll
            for (int ks = 0; ks < 12; ++ks) {
                int cb = ks & 3;
                v8s a0 = (ks >= 8) ? Alo[0][cb] : Ahi[0][cb];
                v8s a1 = (ks >= 8) ? Alo[1][cb] : Ahi[1][cb];
                int kb = ks * 32 + fq * 8;
                v8s b0 = *(const v8s*)(Wb + (size_t)(n0 + fr) * 384 + kb);
                v8s b1 = *(const v8s*)(Wb + (size_t)(n0 + 16 + fr) * 384 + kb);
                a2[0][0] = __builtin_amdgcn_mfma_f32_16x16x32_bf16(a0, b0, a2[0][0], 0, 0, 0);
                a2[0][1] = __builtin_amdgcn_mfma_f32_16x16x32_bf16(a0, b1, a2[0][1], 0, 0, 0);
                a2[1][0] = __builtin_amdgcn_mfma_f32_16x16x32_bf16(a1, b0, a2[1][0], 0, 0, 0);
                a2[1][1] = __builtin_amdgcn_mfma_f32_16x16x32_bf16(a1, b1, a2[1][1], 0, 0, 0);
            }
            #pragma unroll
            for (int i = 0; i < 2; ++i)
                #pragma unroll
                for (int j = 0; j < 2; ++j)
                    #pragma unroll
                    for (int rr = 0; rr < 4; ++rr)
                        kv_s[m0 + 16 * i + fq * 4 + rr][n0 + 16 * j + fr] = a2[i][j][rr];
        }
        __syncthreads();

        // B2: scores, one 8-lane group per slot (64 slots)
        {
            const int jl = tid >> 3, oct = tid & 7;
            float p = 0.f;
            #pragma unroll
            for (int kk = 0; kk < 16; ++kk) {
                int k = oct * 16 + kk;
                p = fmaf(tanh_n(q_s[k] + kv_s[jl][k]), w2s[k], p);
            }
            p = oct_rsum(p);
            if (oct == 0) s_s[jl] = (jt * 64 + jl < 255) ? p : 0.0f;
        }
        __syncthreads();

        // B3: attn partial: racc += s[j] * H[j][d] over this tile's 16 j/grp
        #pragma unroll 4
        for (int u = 0; u < 16; ++u) {
            int lj = grp * 16 + u;
            racc = fmaf(s_s[lj], Hb[(size_t)(jt * 64 + lj) * Hsz + d_att], racc);
        }
        __syncthreads();   // protect kv_s / s_s before next jt overwrites
    }

    part4[grp][d_att] = racc;
    __syncthreads();
    if (tid < Hsz)
        r_s[tid] = hT_s[tid] + part4[0][tid] + part4[1][tid] + part4[2][tid] + part4[3][tid];
    __syncthreads();

    // Phase C: out[b] = r @ w_fc^T + b_fc (one quad per output)
    {
        const int o = tid >> 2;
        float acc = 0.f;
        if (o < Csz) {
            #pragma unroll 8
            for (int kk = 0; kk < 32; ++kk) {
                int k = q * 32 + kk;
                acc = fmaf(r_s[k], w_fc[(size_t)o * Hsz + k], acc);
            }
        }
        acc = quad_rsum(acc);
        if (q == 0 && o < Csz) out[b * Csz + o] = acc + b_fc[o];
    }
}

// ---------------- launch ----------------
extern "C" void kernel_launch(void* const* d_in, const int* in_sizes, int n_in,
                              void* d_out, int out_size, void* d_ws, size_t ws_size,
                              hipStream_t stream) {
    const float* x    = (const float*)d_in[0];
    const float* w_ih = (const float*)d_in[1];
    const float* b_ih = (const float*)d_in[2];
    const float* w_hh = (const float*)d_in[3];
    const float* b_hh = (const float*)d_in[4];
    const float* w1   = (const float*)d_in[5];
    const float* w2   = (const float*)d_in[6];
    const float* w_fc = (const float*)d_in[7];
    const float* b_fc = (const float*)d_in[8];

    float* ws = (float*)d_ws;
    float* whh_pk = ws;                                      // 65536 f
    __hip_bfloat16* W2v = (__hip_bfloat16*)(whh_pk + 65536); // 24576 f worth
    float* G      = whh_pk + 65536 + 24576;                  // 4194304 f
    float* H_all  = G + 4194304;                             // 1048576 f
    // total ~5.33M floats ~= 21.3 MB

    gemm_prep<<<1408, 256, 0, stream>>>(x, w_ih, b_ih, w_hh, b_hh, w1,
                                        W2v, whh_pk, G);

    lstm_fused<<<Bsz, 512, 0, stream>>>(G, whh_pk, W2v, w1, w2, w_fc, b_fc,
                                        H_all, (float*)d_out);
}